// Round 11
// baseline (351.853 us; speedup 1.0000x reference)
//
#include <hip/hip_runtime.h>
#include <math.h>

#define D_DIM 256
#define H_DIM 128
#define RTILE 16
#define XSTRIDE 260   // dwords per LDS row; mod 32 == 4 -> bank-balanced b128 reads

typedef __attribute__((ext_vector_type(8))) short bf16x8;
typedef __attribute__((ext_vector_type(4))) float f32x4;

__device__ __forceinline__ unsigned short f32_to_bf16(float f) {
  unsigned int u = __float_as_uint(f);
  u += 0x7FFFu + ((u >> 16) & 1u);          // RTNE (setup kernel only)
  return (unsigned short)(u >> 16);
}

// two f32 -> packed bf16 pair (round-half-up); MFMA input only
__device__ __forceinline__ unsigned int pack2_rn(float f0, float f1) {
  unsigned int u0 = (__float_as_uint(f0) + 0x8000u) & 0xFFFF0000u;
  unsigned int u1 = (__float_as_uint(f1) + 0x8000u) & 0xFFFF0000u;
  return (u0 >> 16) | u1;
}

__device__ __forceinline__ float tanh_fast(float x) {
  float e = __expf(2.0f * x);
  return 1.0f - 2.0f / (e + 1.0f);
}

// ---------------------------------------------------------------------------
// Setup: W1 -> per-lane bf16 B-fragments, ALL 8 col-tiles per lane.
// Fragment f = kt*8+nt, lane l (q=l>>4, c=l&15):
//   elem j = W1[kt*32 + q*8 + j][nt*16 + c]
// Stored at wfrag[(f*64 + l)*8 + j]  (64 KB total, L2/L1-resident).
// ---------------------------------------------------------------------------
__global__ void setup_w1_kernel(const float* __restrict__ W1,
                                unsigned short* __restrict__ wfrag)
{
  const int t = threadIdx.x;            // 256 threads
  const int l = t & 63, q = l >> 4, c = l & 15;
  const int f0 = (t >> 6) * 16;         // 16 fragments per thread group
  for (int f = f0; f < f0 + 16; ++f) {
    int kt = f >> 3, nt = f & 7;
#pragma unroll
    for (int j = 0; j < 8; ++j)
      wfrag[((size_t)f * 64 + l) * 8 + j] =
          f32_to_bf16(W1[(kt * 32 + q * 8 + j) * H_DIM + nt * 16 + c]);
  }
}

// ---------------------------------------------------------------------------
// Segment start offsets (batch sorted; int32/int64 runtime detect).
// ---------------------------------------------------------------------------
__global__ void offsets_kernel(const void* __restrict__ batch, int* __restrict__ start,
                               int N, int G)
{
  int g = blockIdx.x * blockDim.x + threadIdx.x;
  if (g > G) return;
  const int* b32 = (const int*)batch;
  bool is64 = (b32[N - 1] != G - 1);
  int lo = 0, hi = N;
  while (lo < hi) {
    int mid = (lo + hi) >> 1;
    long long v = is64 ? ((const long long*)batch)[mid] : (long long)b32[mid];
    if (v < (long long)g) lo = mid + 1; else hi = mid;
  }
  start[g] = lo;
}

// ---------------------------------------------------------------------------
// ONE WAVE PER GRAPH. Zero barriers. Per 16-row tile:
//   load 16 rows (1 float4/lane/row) -> LDS f32 (private region)
//   A-frags converted on the fly (each element once), 64 MFMA (8 kt x 8 nt)
//   wave-local online softmax (q-group shfl trees, no LDS exchange)
//   pool from LDS: lane owns dims 4l..4l+3; output = single float4 store
// ---------------------------------------------------------------------------
__global__ __launch_bounds__(64, 1)
void fused1w_kernel(const float* __restrict__ x, const unsigned short* __restrict__ wfrag,
                    const float* __restrict__ b1, const float* __restrict__ W2,
                    const int* __restrict__ start, float* __restrict__ out, int N)
{
  __shared__ float xs[RTILE][XSTRIDE];   // 16.25 KB -> 9 blocks/CU

  const int g = blockIdx.x;
  const int l = threadIdx.x;             // 0..63
  const int s = start[g], e = start[g + 1];
  const int l4 = l * 4;

  if (s >= e) {
    float4 z = {0.f, 0.f, 0.f, 0.f};
    *reinterpret_cast<float4*>(out + (size_t)g * D_DIM + l4) = z;
    return;
  }
  const int len = e - s;
  const int c = l & 15, q = l >> 4;

  const bf16x8* wfv = (const bf16x8*)wfrag;

  float b1c[8], w2c[8];
#pragma unroll
  for (int nt = 0; nt < 8; ++nt) {
    b1c[nt] = b1[nt * 16 + c];
    w2c[nt] = W2[nt * 16 + c];
  }

  float m_run = -INFINITY, Z = 0.f;
  float p0 = 0.f, p1 = 0.f, p2 = 0.f, p3 = 0.f;

  const int nT = (len + RTILE - 1) / RTILE;
  for (int ti = 0; ti < nT; ++ti) {
    const int t0 = ti * RTILE;
    const int iend = min(RTILE, len - t0);

    // ---- load + stage 16 rows (coalesced 1 KB/row; clamped pads) ----
#pragma unroll
    for (int r = 0; r < RTILE; ++r) {
      int gr = min(s + t0 + r, N - 1);
      float4 v = *reinterpret_cast<const float4*>(x + (size_t)gr * D_DIM + l4);
      *reinterpret_cast<float4*>(&xs[r][l4]) = v;
    }
    // (wave-internal lgkmcnt ordering; no barrier needed)

    // ---- MFMA: 16 rows x 128 cols, K=256 ----
    f32x4 acc[8];
#pragma unroll
    for (int nt = 0; nt < 8; ++nt) acc[nt] = (f32x4){0.f, 0.f, 0.f, 0.f};

#pragma unroll
    for (int kt = 0; kt < 8; ++kt) {
      float4 a0 = *reinterpret_cast<const float4*>(&xs[c][kt * 32 + q * 8]);
      float4 a1 = *reinterpret_cast<const float4*>(&xs[c][kt * 32 + q * 8 + 4]);
      uint4 F;
      F.x = pack2_rn(a0.x, a0.y);
      F.y = pack2_rn(a0.z, a0.w);
      F.z = pack2_rn(a1.x, a1.y);
      F.w = pack2_rn(a1.z, a1.w);
      bf16x8 ah = *reinterpret_cast<const bf16x8*>(&F);
#pragma unroll
      for (int nt = 0; nt < 8; ++nt)
        acc[nt] = __builtin_amdgcn_mfma_f32_16x16x32_bf16(
            ah, wfv[(kt * 8 + nt) * 64 + l], acc[nt], 0, 0, 0);
    }

    // ---- logits: tanh + W2 dot, reduce over the 16 c-lanes ----
    float lg0 = 0.f, lg1 = 0.f, lg2 = 0.f, lg3 = 0.f;
#pragma unroll
    for (int nt = 0; nt < 8; ++nt) {
      lg0 += tanh_fast(acc[nt][0] + b1c[nt]) * w2c[nt];
      lg1 += tanh_fast(acc[nt][1] + b1c[nt]) * w2c[nt];
      lg2 += tanh_fast(acc[nt][2] + b1c[nt]) * w2c[nt];
      lg3 += tanh_fast(acc[nt][3] + b1c[nt]) * w2c[nt];
    }
#pragma unroll
    for (int o = 1; o < 16; o <<= 1) {
      lg0 += __shfl_xor(lg0, o, 64);
      lg1 += __shfl_xor(lg1, o, 64);
      lg2 += __shfl_xor(lg2, o, 64);
      lg3 += __shfl_xor(lg3, o, 64);
    }
    // lane now holds full logits for rows q*4 + {0,1,2,3}; mask pads
    if (q * 4 + 0 >= iend) lg0 = -INFINITY;
    if (q * 4 + 1 >= iend) lg1 = -INFINITY;
    if (q * 4 + 2 >= iend) lg2 = -INFINITY;
    if (q * 4 + 3 >= iend) lg3 = -INFINITY;

    // ---- wave-local online softmax (reduce across q-groups: o=16,32) ----
    float tmax = fmaxf(fmaxf(lg0, lg1), fmaxf(lg2, lg3));
    tmax = fmaxf(tmax, __shfl_xor(tmax, 16, 64));
    tmax = fmaxf(tmax, __shfl_xor(tmax, 32, 64));
    float m_new = fmaxf(m_run, tmax);
    float scale = __expf(m_run - m_new);         // first tile: exp(-inf)=0
    float e0 = __expf(lg0 - m_new);
    float e1 = __expf(lg1 - m_new);
    float e2 = __expf(lg2 - m_new);
    float e3 = __expf(lg3 - m_new);
    float esum = (e0 + e1) + (e2 + e3);
    esum += __shfl_xor(esum, 16, 64);
    esum += __shfl_xor(esum, 32, 64);
    Z = Z * scale + esum;
    m_run = m_new;

    // ---- pool: lane owns dims l4..l4+3; e_r broadcast from q-group r>>2 ----
    p0 *= scale; p1 *= scale; p2 *= scale; p3 *= scale;
#define POOL_ROW(RR, EV)                                                     \
    {                                                                        \
      float er = __shfl(EV, ((RR) >> 2) * 16, 64);                           \
      float4 xv = *reinterpret_cast<const float4*>(&xs[RR][l4]);             \
      p0 = fmaf(er, xv.x, p0);                                               \
      p1 = fmaf(er, xv.y, p1);                                               \
      p2 = fmaf(er, xv.z, p2);                                               \
      p3 = fmaf(er, xv.w, p3);                                               \
    }
    POOL_ROW(0,  e0) POOL_ROW(1,  e1) POOL_ROW(2,  e2) POOL_ROW(3,  e3)
    POOL_ROW(4,  e0) POOL_ROW(5,  e1) POOL_ROW(6,  e2) POOL_ROW(7,  e3)
    POOL_ROW(8,  e0) POOL_ROW(9,  e1) POOL_ROW(10, e2) POOL_ROW(11, e3)
    POOL_ROW(12, e0) POOL_ROW(13, e1) POOL_ROW(14, e2) POOL_ROW(15, e3)
#undef POOL_ROW
  }

  float invZ = 1.0f / Z;
  float4 o4 = {p0 * invZ, p1 * invZ, p2 * invZ, p3 * invZ};
  *reinterpret_cast<float4*>(out + (size_t)g * D_DIM + l4) = o4;
}

// ---------------------------------------------------------------------------
extern "C" void kernel_launch(void* const* d_in, const int* in_sizes, int n_in,
                              void* d_out, int out_size, void* d_ws, size_t ws_size,
                              hipStream_t stream)
{
  const float* x     = (const float*)d_in[0];
  const void*  batch = d_in[1];
  const float* W1    = (const float*)d_in[2];
  const float* b1    = (const float*)d_in[3];
  const float* W2    = (const float*)d_in[4];
  // d_in[5] = b2: cancels exactly in the segment softmax -> unused.

  const int N = in_sizes[0] / D_DIM;     // 500000
  const int G = out_size / D_DIM;        // 4096

  unsigned short* wfrag = (unsigned short*)d_ws;              // 64 KB
  int* startA = (int*)((char*)d_ws + 64 * 64 * 8 * sizeof(unsigned short));
  float* out = (float*)d_out;

  setup_w1_kernel<<<1, 256, 0, stream>>>(W1, wfrag);
  offsets_kernel<<<(G + 1 + 255) / 256, 256, 0, stream>>>(batch, startA, N, G);
  fused1w_kernel<<<G, 64, 0, stream>>>(x, wfrag, b1, W2, startA, out, N);
}

// Round 12
// 320.656 us; speedup vs baseline: 1.0973x; 1.0973x over previous
//
#include <hip/hip_runtime.h>
#include <math.h>

#define D_DIM 256
#define H_DIM 128
#define RTILE 16
#define XSTRIDE 260   // dwords per LDS row; 1040 B stride, mod-32-banks = 4

typedef __attribute__((ext_vector_type(8))) short bf16x8;
typedef __attribute__((ext_vector_type(4))) float f32x4;

__device__ __forceinline__ unsigned short f32_to_bf16(float f) {
  unsigned int u = __float_as_uint(f);
  u += 0x7FFFu + ((u >> 16) & 1u);          // RTNE (setup kernel only)
  return (unsigned short)(u >> 16);
}

// two f32 -> packed bf16 pair (round-half-up); MFMA input only
__device__ __forceinline__ unsigned int pack2_rn(float f0, float f1) {
  unsigned int u0 = (__float_as_uint(f0) + 0x8000u) & 0xFFFF0000u;
  unsigned int u1 = (__float_as_uint(f1) + 0x8000u) & 0xFFFF0000u;
  return (u0 >> 16) | u1;
}

__device__ __forceinline__ float tanh_fast(float x) {
  float e = __expf(2.0f * x);
  return 1.0f - 2.0f / (e + 1.0f);
}

// HBM -> LDS direct DMA, 16 B/lane. ldst is the wave-uniform row base;
// HW writes lane l at ldst + l*16 (m104 semantics). gsrc is per-lane.
__device__ __forceinline__ void gload_lds16(const float* gsrc, float* ldst) {
  __builtin_amdgcn_global_load_lds(
      (const __attribute__((address_space(1))) unsigned int*)gsrc,
      (__attribute__((address_space(3))) unsigned int*)ldst,
      16, 0, 0);
}

// ---------------------------------------------------------------------------
// Setup: W1 -> per-lane bf16 B-fragments, all 8 col-tiles per lane.
// Fragment f = kt*8+nt, lane l (q=l>>4, c=l&15):
//   elem j = W1[kt*32 + q*8 + j][nt*16 + c]
// ---------------------------------------------------------------------------
__global__ void setup_w1_kernel(const float* __restrict__ W1,
                                unsigned short* __restrict__ wfrag)
{
  const int t = threadIdx.x;            // 256 threads
  const int l = t & 63, q = l >> 4, c = l & 15;
  const int f0 = (t >> 6) * 16;
  for (int f = f0; f < f0 + 16; ++f) {
    int kt = f >> 3, nt = f & 7;
#pragma unroll
    for (int j = 0; j < 8; ++j)
      wfrag[((size_t)f * 64 + l) * 8 + j] =
          f32_to_bf16(W1[(kt * 32 + q * 8 + j) * H_DIM + nt * 16 + c]);
  }
}

// ---------------------------------------------------------------------------
// Segment start offsets (batch sorted; int32/int64 runtime detect).
// ---------------------------------------------------------------------------
__global__ void offsets_kernel(const void* __restrict__ batch, int* __restrict__ start,
                               int N, int G)
{
  int g = blockIdx.x * blockDim.x + threadIdx.x;
  if (g > G) return;
  const int* b32 = (const int*)batch;
  bool is64 = (b32[N - 1] != G - 1);
  int lo = 0, hi = N;
  while (lo < hi) {
    int mid = (lo + hi) >> 1;
    long long v = is64 ? ((const long long*)batch)[mid] : (long long)b32[mid];
    if (v < (long long)g) lo = mid + 1; else hi = mid;
  }
  start[g] = lo;
}

// ---------------------------------------------------------------------------
// ONE WAVE PER GRAPH, zero barriers (R11 structure). R12 changes:
//  - staging via global_load_lds (no staging VGPRs, no reg round-trip)
//  - __launch_bounds__(64,4): VGPR cap 128 -> target 9+ blocks/CU
// Per 16-row tile: DMA rows -> LDS f32; vmcnt(0); A-frags converted on the
// fly; 64 MFMA; wave-local online softmax (shfl trees); pool from LDS
// (lane owns dims 4l..4l+3); single float4 store per graph at the end.
// ---------------------------------------------------------------------------
__global__ __launch_bounds__(64, 4)
void fused1w_kernel(const float* __restrict__ x, const unsigned short* __restrict__ wfrag,
                    const float* __restrict__ b1, const float* __restrict__ W2,
                    const int* __restrict__ start, float* __restrict__ out, int N)
{
  __shared__ float xs[RTILE][XSTRIDE];   // 16.25 KB -> 9 blocks/CU (LDS limit)

  const int g = blockIdx.x;
  const int l = threadIdx.x;             // 0..63
  const int s = start[g], e = start[g + 1];
  const int l4 = l * 4;

  if (s >= e) {
    float4 z = {0.f, 0.f, 0.f, 0.f};
    *reinterpret_cast<float4*>(out + (size_t)g * D_DIM + l4) = z;
    return;
  }
  const int len = e - s;
  const int c = l & 15, q = l >> 4;

  const bf16x8* wfv = (const bf16x8*)wfrag;

  float b1c[8], w2c[8];
#pragma unroll
  for (int nt = 0; nt < 8; ++nt) {
    b1c[nt] = b1[nt * 16 + c];
    w2c[nt] = W2[nt * 16 + c];
  }

  float m_run = -INFINITY, Z = 0.f;
  float p0 = 0.f, p1 = 0.f, p2 = 0.f, p3 = 0.f;

  const int nT = (len + RTILE - 1) / RTILE;
  for (int ti = 0; ti < nT; ++ti) {
    const int t0 = ti * RTILE;
    const int iend = min(RTILE, len - t0);

    // ---- DMA 16 rows HBM -> LDS (1 inst/row, no registers) ----
#pragma unroll
    for (int r = 0; r < RTILE; ++r) {
      int gr = min(s + t0 + r, N - 1);
      gload_lds16(x + (size_t)gr * D_DIM + l4, &xs[r][0]);
    }
    asm volatile("s_waitcnt vmcnt(0)" ::: "memory");   // wave-local drain

    // ---- MFMA: 16 rows x 128 cols, K=256 ----
    f32x4 acc[8];
#pragma unroll
    for (int nt = 0; nt < 8; ++nt) acc[nt] = (f32x4){0.f, 0.f, 0.f, 0.f};

#pragma unroll
    for (int kt = 0; kt < 8; ++kt) {
      float4 a0 = *reinterpret_cast<const float4*>(&xs[c][kt * 32 + q * 8]);
      float4 a1 = *reinterpret_cast<const float4*>(&xs[c][kt * 32 + q * 8 + 4]);
      uint4 F;
      F.x = pack2_rn(a0.x, a0.y);
      F.y = pack2_rn(a0.z, a0.w);
      F.z = pack2_rn(a1.x, a1.y);
      F.w = pack2_rn(a1.z, a1.w);
      bf16x8 ah = *reinterpret_cast<const bf16x8*>(&F);
#pragma unroll
      for (int nt = 0; nt < 8; ++nt)
        acc[nt] = __builtin_amdgcn_mfma_f32_16x16x32_bf16(
            ah, wfv[(kt * 8 + nt) * 64 + l], acc[nt], 0, 0, 0);
    }

    // ---- logits: tanh + W2 dot, reduce over the 16 c-lanes ----
    float lg0 = 0.f, lg1 = 0.f, lg2 = 0.f, lg3 = 0.f;
#pragma unroll
    for (int nt = 0; nt < 8; ++nt) {
      lg0 += tanh_fast(acc[nt][0] + b1c[nt]) * w2c[nt];
      lg1 += tanh_fast(acc[nt][1] + b1c[nt]) * w2c[nt];
      lg2 += tanh_fast(acc[nt][2] + b1c[nt]) * w2c[nt];
      lg3 += tanh_fast(acc[nt][3] + b1c[nt]) * w2c[nt];
    }
#pragma unroll
    for (int o = 1; o < 16; o <<= 1) {
      lg0 += __shfl_xor(lg0, o, 64);
      lg1 += __shfl_xor(lg1, o, 64);
      lg2 += __shfl_xor(lg2, o, 64);
      lg3 += __shfl_xor(lg3, o, 64);
    }
    // lane holds full logits for rows q*4 + {0,1,2,3}; mask pads
    if (q * 4 + 0 >= iend) lg0 = -INFINITY;
    if (q * 4 + 1 >= iend) lg1 = -INFINITY;
    if (q * 4 + 2 >= iend) lg2 = -INFINITY;
    if (q * 4 + 3 >= iend) lg3 = -INFINITY;

    // ---- wave-local online softmax (reduce across q-groups: o=16,32) ----
    float tmax = fmaxf(fmaxf(lg0, lg1), fmaxf(lg2, lg3));
    tmax = fmaxf(tmax, __shfl_xor(tmax, 16, 64));
    tmax = fmaxf(tmax, __shfl_xor(tmax, 32, 64));
    float m_new = fmaxf(m_run, tmax);
    float scale = __expf(m_run - m_new);         // first tile: exp(-inf)=0
    float e0 = __expf(lg0 - m_new);
    float e1 = __expf(lg1 - m_new);
    float e2 = __expf(lg2 - m_new);
    float e3 = __expf(lg3 - m_new);
    float esum = (e0 + e1) + (e2 + e3);
    esum += __shfl_xor(esum, 16, 64);
    esum += __shfl_xor(esum, 32, 64);
    Z = Z * scale + esum;
    m_run = m_new;

    // ---- pool: lane owns dims l4..l4+3; e_r broadcast from q-group r>>2 ----
    p0 *= scale; p1 *= scale; p2 *= scale; p3 *= scale;
#define POOL_ROW(RR, EV)                                                     \
    {                                                                        \
      float er = __shfl(EV, ((RR) >> 2) * 16, 64);                           \
      float4 xv = *reinterpret_cast<const float4*>(&xs[RR][l4]);             \
      p0 = fmaf(er, xv.x, p0);                                               \
      p1 = fmaf(er, xv.y, p1);                                               \
      p2 = fmaf(er, xv.z, p2);                                               \
      p3 = fmaf(er, xv.w, p3);                                               \
    }
    POOL_ROW(0,  e0) POOL_ROW(1,  e1) POOL_ROW(2,  e2) POOL_ROW(3,  e3)
    POOL_ROW(4,  e0) POOL_ROW(5,  e1) POOL_ROW(6,  e2) POOL_ROW(7,  e3)
    POOL_ROW(8,  e0) POOL_ROW(9,  e1) POOL_ROW(10, e2) POOL_ROW(11, e3)
    POOL_ROW(12, e0) POOL_ROW(13, e1) POOL_ROW(14, e2) POOL_ROW(15, e3)
#undef POOL_ROW
    // pool ds_reads are consumed (fma) before loop-back -> next DMA is safe
  }

  float invZ = 1.0f / Z;
  float4 o4 = {p0 * invZ, p1 * invZ, p2 * invZ, p3 * invZ};
  *reinterpret_cast<float4*>(out + (size_t)g * D_DIM + l4) = o4;
}

// ---------------------------------------------------------------------------
extern "C" void kernel_launch(void* const* d_in, const int* in_sizes, int n_in,
                              void* d_out, int out_size, void* d_ws, size_t ws_size,
                              hipStream_t stream)
{
  const float* x     = (const float*)d_in[0];
  const void*  batch = d_in[1];
  const float* W1    = (const float*)d_in[2];
  const float* b1    = (const float*)d_in[3];
  const float* W2    = (const float*)d_in[4];
  // d_in[5] = b2: cancels exactly in the segment softmax -> unused.

  const int N = in_sizes[0] / D_DIM;     // 500000
  const int G = out_size / D_DIM;        // 4096

  unsigned short* wfrag = (unsigned short*)d_ws;              // 64 KB
  int* startA = (int*)((char*)d_ws + 64 * 64 * 8 * sizeof(unsigned short));
  float* out = (float*)d_out;

  setup_w1_kernel<<<1, 256, 0, stream>>>(W1, wfrag);
  offsets_kernel<<<(G + 1 + 255) / 256, 256, 0, stream>>>(batch, startA, N, G);
  fused1w_kernel<<<G, 64, 0, stream>>>(x, wfrag, b1, W2, startA, out, N);
}

// Round 13
// 316.711 us; speedup vs baseline: 1.1110x; 1.0125x over previous
//
#include <hip/hip_runtime.h>
#include <math.h>

#define D_DIM 256
#define H_DIM 128
#define RTILE 16
#define XSTRIDE 260   // dwords per LDS row; 1040 B stride (16B-aligned rows)
#define WPB 4         // independent wave-pipelines per workgroup

typedef __attribute__((ext_vector_type(8))) short bf16x8;
typedef __attribute__((ext_vector_type(4))) float f32x4;

__device__ __forceinline__ unsigned short f32_to_bf16(float f) {
  unsigned int u = __float_as_uint(f);
  u += 0x7FFFu + ((u >> 16) & 1u);          // RTNE (setup kernel only)
  return (unsigned short)(u >> 16);
}

// two f32 -> packed bf16 pair (round-half-up); MFMA input only
__device__ __forceinline__ unsigned int pack2_rn(float f0, float f1) {
  unsigned int u0 = (__float_as_uint(f0) + 0x8000u) & 0xFFFF0000u;
  unsigned int u1 = (__float_as_uint(f1) + 0x8000u) & 0xFFFF0000u;
  return (u0 >> 16) | u1;
}

__device__ __forceinline__ float tanh_fast(float x) {
  float e = __expf(2.0f * x);
  return 1.0f - 2.0f / (e + 1.0f);
}

// HBM -> LDS direct DMA, 16 B/lane: lane l writes ldst + l*16 (m104 semantics).
__device__ __forceinline__ void gload_lds16(const float* gsrc, float* ldst) {
  __builtin_amdgcn_global_load_lds(
      (const __attribute__((address_space(1))) unsigned int*)gsrc,
      (__attribute__((address_space(3))) unsigned int*)ldst,
      16, 0, 0);
}

// ---------------------------------------------------------------------------
// Setup: W1 -> per-lane bf16 B-fragments, all 8 col-tiles per lane.
// Fragment f = kt*8+nt, lane l (q=l>>4, c=l&15):
//   elem j = W1[kt*32 + q*8 + j][nt*16 + c]
// ---------------------------------------------------------------------------
__global__ void setup_w1_kernel(const float* __restrict__ W1,
                                unsigned short* __restrict__ wfrag)
{
  const int t = threadIdx.x;            // 256 threads
  const int l = t & 63, q = l >> 4, c = l & 15;
  const int f0 = (t >> 6) * 16;
  for (int f = f0; f < f0 + 16; ++f) {
    int kt = f >> 3, nt = f & 7;
#pragma unroll
    for (int j = 0; j < 8; ++j)
      wfrag[((size_t)f * 64 + l) * 8 + j] =
          f32_to_bf16(W1[(kt * 32 + q * 8 + j) * H_DIM + nt * 16 + c]);
  }
}

// ---------------------------------------------------------------------------
// Segment start offsets (batch sorted; int32/int64 runtime detect).
// ---------------------------------------------------------------------------
__global__ void offsets_kernel(const void* __restrict__ batch, int* __restrict__ start,
                               int N, int G)
{
  int g = blockIdx.x * blockDim.x + threadIdx.x;
  if (g > G) return;
  const int* b32 = (const int*)batch;
  bool is64 = (b32[N - 1] != G - 1);
  int lo = 0, hi = N;
  while (lo < hi) {
    int mid = (lo + hi) >> 1;
    long long v = is64 ? ((const long long*)batch)[mid] : (long long)b32[mid];
    if (v < (long long)g) lo = mid + 1; else hi = mid;
  }
  start[g] = lo;
}

// ---------------------------------------------------------------------------
// 4 INDEPENDENT WAVE-PIPELINES PER WORKGROUP (zero barriers). Wave w owns
// graph blockIdx*4+w and LDS slice xs[w]. Per 16-row tile (R12 pipeline):
//   DMA rows -> LDS f32 (global_load_lds, no staging regs); vmcnt(0);
//   A-frags packed on the fly; 64 MFMA; wave-local online softmax (shfl
//   trees); pool from LDS (lane owns dims 4l..4l+3); one float4 store.
// Rationale: scheduler hosts only ~2.5-3.3 WORKGROUPS/CU regardless of
// resources (R2/R5/R11/R12 evidence) -> pack waves into fewer workgroups.
// ---------------------------------------------------------------------------
__global__ __launch_bounds__(256, 2)
void fused4w_kernel(const float* __restrict__ x, const unsigned short* __restrict__ wfrag,
                    const float* __restrict__ b1, const float* __restrict__ W2,
                    const int* __restrict__ start, float* __restrict__ out, int N, int G)
{
  __shared__ float xs[WPB][RTILE][XSTRIDE];   // 66.6 KB -> 2 blocks/CU

  const int tid = threadIdx.x;
  const int wv = tid >> 6;               // 0..3: pipeline id
  const int l = tid & 63;
  const int g = blockIdx.x * WPB + wv;
  if (g >= G) return;

  const int s = start[g], e = start[g + 1];
  const int l4 = l * 4;

  if (s >= e) {
    float4 z = {0.f, 0.f, 0.f, 0.f};
    *reinterpret_cast<float4*>(out + (size_t)g * D_DIM + l4) = z;
    return;
  }
  const int len = e - s;
  const int c = l & 15, q = l >> 4;

  const bf16x8* wfv = (const bf16x8*)wfrag;

  float b1c[8], w2c[8];
#pragma unroll
  for (int nt = 0; nt < 8; ++nt) {
    b1c[nt] = b1[nt * 16 + c];
    w2c[nt] = W2[nt * 16 + c];
  }

  float m_run = -INFINITY, Z = 0.f;
  float p0 = 0.f, p1 = 0.f, p2 = 0.f, p3 = 0.f;

  const int nT = (len + RTILE - 1) / RTILE;
  for (int ti = 0; ti < nT; ++ti) {
    const int t0 = ti * RTILE;
    const int iend = min(RTILE, len - t0);

    // ---- DMA 16 rows HBM -> this wave's LDS slice ----
#pragma unroll
    for (int r = 0; r < RTILE; ++r) {
      int gr = min(s + t0 + r, N - 1);
      gload_lds16(x + (size_t)gr * D_DIM + l4, &xs[wv][r][0]);
    }
    asm volatile("s_waitcnt vmcnt(0)" ::: "memory");   // wave-local drain

    // ---- MFMA: 16 rows x 128 cols, K=256 ----
    f32x4 acc[8];
#pragma unroll
    for (int nt = 0; nt < 8; ++nt) acc[nt] = (f32x4){0.f, 0.f, 0.f, 0.f};

#pragma unroll
    for (int kt = 0; kt < 8; ++kt) {
      float4 a0 = *reinterpret_cast<const float4*>(&xs[wv][c][kt * 32 + q * 8]);
      float4 a1 = *reinterpret_cast<const float4*>(&xs[wv][c][kt * 32 + q * 8 + 4]);
      uint4 F;
      F.x = pack2_rn(a0.x, a0.y);
      F.y = pack2_rn(a0.z, a0.w);
      F.z = pack2_rn(a1.x, a1.y);
      F.w = pack2_rn(a1.z, a1.w);
      bf16x8 ah = *reinterpret_cast<const bf16x8*>(&F);
#pragma unroll
      for (int nt = 0; nt < 8; ++nt)
        acc[nt] = __builtin_amdgcn_mfma_f32_16x16x32_bf16(
            ah, wfv[(kt * 8 + nt) * 64 + l], acc[nt], 0, 0, 0);
    }

    // ---- logits: tanh + W2 dot, reduce over the 16 c-lanes ----
    float lg0 = 0.f, lg1 = 0.f, lg2 = 0.f, lg3 = 0.f;
#pragma unroll
    for (int nt = 0; nt < 8; ++nt) {
      lg0 += tanh_fast(acc[nt][0] + b1c[nt]) * w2c[nt];
      lg1 += tanh_fast(acc[nt][1] + b1c[nt]) * w2c[nt];
      lg2 += tanh_fast(acc[nt][2] + b1c[nt]) * w2c[nt];
      lg3 += tanh_fast(acc[nt][3] + b1c[nt]) * w2c[nt];
    }
#pragma unroll
    for (int o = 1; o < 16; o <<= 1) {
      lg0 += __shfl_xor(lg0, o, 64);
      lg1 += __shfl_xor(lg1, o, 64);
      lg2 += __shfl_xor(lg2, o, 64);
      lg3 += __shfl_xor(lg3, o, 64);
    }
    // lane holds full logits for rows q*4 + {0,1,2,3}; mask pads
    if (q * 4 + 0 >= iend) lg0 = -INFINITY;
    if (q * 4 + 1 >= iend) lg1 = -INFINITY;
    if (q * 4 + 2 >= iend) lg2 = -INFINITY;
    if (q * 4 + 3 >= iend) lg3 = -INFINITY;

    // ---- wave-local online softmax (reduce across q-groups: o=16,32) ----
    float tmax = fmaxf(fmaxf(lg0, lg1), fmaxf(lg2, lg3));
    tmax = fmaxf(tmax, __shfl_xor(tmax, 16, 64));
    tmax = fmaxf(tmax, __shfl_xor(tmax, 32, 64));
    float m_new = fmaxf(m_run, tmax);
    float scale = __expf(m_run - m_new);         // first tile: exp(-inf)=0
    float e0 = __expf(lg0 - m_new);
    float e1 = __expf(lg1 - m_new);
    float e2 = __expf(lg2 - m_new);
    float e3 = __expf(lg3 - m_new);
    float esum = (e0 + e1) + (e2 + e3);
    esum += __shfl_xor(esum, 16, 64);
    esum += __shfl_xor(esum, 32, 64);
    Z = Z * scale + esum;
    m_run = m_new;

    // ---- pool: lane owns dims l4..l4+3; e_r broadcast from q-group r>>2 ----
    p0 *= scale; p1 *= scale; p2 *= scale; p3 *= scale;
#define POOL_ROW(RR, EV)                                                     \
    {                                                                        \
      float er = __shfl(EV, ((RR) >> 2) * 16, 64);                           \
      float4 xv = *reinterpret_cast<const float4*>(&xs[wv][RR][l4]);         \
      p0 = fmaf(er, xv.x, p0);                                               \
      p1 = fmaf(er, xv.y, p1);                                               \
      p2 = fmaf(er, xv.z, p2);                                               \
      p3 = fmaf(er, xv.w, p3);                                               \
    }
    POOL_ROW(0,  e0) POOL_ROW(1,  e1) POOL_ROW(2,  e2) POOL_ROW(3,  e3)
    POOL_ROW(4,  e0) POOL_ROW(5,  e1) POOL_ROW(6,  e2) POOL_ROW(7,  e3)
    POOL_ROW(8,  e0) POOL_ROW(9,  e1) POOL_ROW(10, e2) POOL_ROW(11, e3)
    POOL_ROW(12, e0) POOL_ROW(13, e1) POOL_ROW(14, e2) POOL_ROW(15, e3)
#undef POOL_ROW
    // pool ds_reads consumed before loop-back -> next DMA into xs[wv] is safe
  }

  float invZ = 1.0f / Z;
  float4 o4 = {p0 * invZ, p1 * invZ, p2 * invZ, p3 * invZ};
  *reinterpret_cast<float4*>(out + (size_t)g * D_DIM + l4) = o4;
}

// ---------------------------------------------------------------------------
extern "C" void kernel_launch(void* const* d_in, const int* in_sizes, int n_in,
                              void* d_out, int out_size, void* d_ws, size_t ws_size,
                              hipStream_t stream)
{
  const float* x     = (const float*)d_in[0];
  const void*  batch = d_in[1];
  const float* W1    = (const float*)d_in[2];
  const float* b1    = (const float*)d_in[3];
  const float* W2    = (const float*)d_in[4];
  // d_in[5] = b2: cancels exactly in the segment softmax -> unused.

  const int N = in_sizes[0] / D_DIM;     // 500000
  const int G = out_size / D_DIM;        // 4096

  unsigned short* wfrag = (unsigned short*)d_ws;              // 64 KB
  int* startA = (int*)((char*)d_ws + 64 * 64 * 8 * sizeof(unsigned short));
  float* out = (float*)d_out;

  setup_w1_kernel<<<1, 256, 0, stream>>>(W1, wfrag);
  offsets_kernel<<<(G + 1 + 255) / 256, 256, 0, stream>>>(batch, startA, N, G);
  fused4w_kernel<<<(G + WPB - 1) / WPB, 256, 0, stream>>>(x, wfrag, b1, W2, startA, out, N, G);
}